// Round 11
// baseline (599.484 us; speedup 1.0000x reference)
//
#include <hip/hip_runtime.h>
#include <hip/hip_bf16.h>

typedef __attribute__((ext_vector_type(8))) short short8;
typedef __attribute__((ext_vector_type(4))) float f32x4;
typedef __attribute__((ext_vector_type(4))) int i32x4;
typedef __attribute__((ext_vector_type(2))) int i32x2;
typedef __attribute__((ext_vector_type(4))) unsigned u32x4;

#define NTOK 512
#define NEXP 16
#define TOPK 4
#define HD   2880
#define ID   2880
#define N1   5760   // 2*I
#define NGRP 90     // 32-value groups per row
#define NKT  45     // HD/64 K-steps
#define ROWB 5760   // A row byte stride (HD*2 == ID*2)

#define NB1 132710400   // b1 elements (E*2I*G_H*16)
#define NS1 8294400     // s1 elements
#define NB2 66355200    // b2 elements
#define NS2 4147200     // s2 elements

__device__ __forceinline__ unsigned perm(unsigned hi, unsigned lo, unsigned sel) {
  return __builtin_amdgcn_perm(hi, lo, sel);
}

// ---------------- perm-LUT MXFP4 dequant (bit-exact bf16, scale folded) ----------------
__device__ __forceinline__ u32x4 dq_word4(unsigned p, unsigned hbl, unsigned hbh,
                                          unsigned lbl, unsigned lbh) {
  unsigned ph = p >> 4;
  unsigned il = p  & 0x07070707u, sl = p  & 0x08080808u;
  unsigned ih = ph & 0x07070707u, sh = ph & 0x08080808u;
  unsigned hbL = perm(hbh, hbl, il) | (sl << 4);
  unsigned lbL = perm(lbh, lbl, il);
  unsigned hbH = perm(hbh, hbl, ih) | (sh << 4);
  unsigned lbH = perm(lbh, lbl, ih);
  unsigned mL01 = perm(hbL, lbL, 0x05010400u);
  unsigned mL23 = perm(hbL, lbL, 0x07030602u);
  unsigned mH01 = perm(hbH, lbH, 0x05010400u);
  unsigned mH23 = perm(hbH, lbH, 0x07030602u);
  u32x4 w;
  w.x = perm(mH01, mL01, 0x05040100u);
  w.y = perm(mH01, mL01, 0x07060302u);
  w.z = perm(mH23, mL23, 0x05040100u);
  w.w = perm(mH23, mL23, 0x07060302u);
  return w;
}

// one B MFMA fragment: 4 packed nibble-bytes (8 values) + scale -> short8 bf16
__device__ __forceinline__ short8 dq_frag(unsigned pk, int sc) {
  unsigned m7 = (unsigned)((127 - sc) << 7);          // sc in [118,127]
  unsigned mm = m7 | (m7 << 16);
  unsigned e10 = (0x3F00u - m7) << 16;                // entry0 stays exact 0
  unsigned e32 = 0x3FC03F80u - mm;
  unsigned e54 = 0x40404000u - mm;
  unsigned e76 = 0x40C04080u - mm;
  unsigned hbl = perm(e32, e10, 0x07050301u);
  unsigned hbh = perm(e76, e54, 0x07050301u);
  unsigned lbl = perm(e32, e10, 0x06040200u);
  unsigned lbh = perm(e76, e54, 0x06040200u);
  u32x4 w = dq_word4(pk, hbl, hbh, lbl, lbh);
  return __builtin_bit_cast(short8, w);
}

// ---------------- int32 -> uint8 repack (pure streaming) ----------------
__global__ __launch_bounds__(256)
void pack_k(const int* __restrict__ in, unsigned char* __restrict__ out, int n16)
{
  int i = blockIdx.x * 256 + threadIdx.x;
  if (i >= n16) return;
  const i32x4* p = (const i32x4*)(in + (size_t)i * 16);
  i32x4 a = p[0], b = p[1], c = p[2], d = p[3];
  u32x4 w;
  w.x = (unsigned)(a.x & 255) | ((unsigned)(a.y & 255) << 8) |
        ((unsigned)(a.z & 255) << 16) | ((unsigned)a.w << 24);
  w.y = (unsigned)(b.x & 255) | ((unsigned)(b.y & 255) << 8) |
        ((unsigned)(b.z & 255) << 16) | ((unsigned)b.w << 24);
  w.z = (unsigned)(c.x & 255) | ((unsigned)(c.y & 255) << 8) |
        ((unsigned)(c.z & 255) << 16) | ((unsigned)c.w << 24);
  w.w = (unsigned)(d.x & 255) | ((unsigned)(d.y & 255) << 8) |
        ((unsigned)(d.z & 255) << 16) | ((unsigned)d.w << 24);
  *(u32x4*)(out + (size_t)i * 16) = w;
}

// ---------------- RMSNorm (also zeroes cnt) ----------------
__global__ __launch_bounds__(256)
void rmsnorm_k(const float* __restrict__ x, const float* __restrict__ nsc,
               float* __restrict__ tf, __hip_bfloat16* __restrict__ tb,
               int* __restrict__ cnt)
{
  int t = blockIdx.x;
  if (t == 0 && threadIdx.x < NEXP) cnt[threadIdx.x] = 0;
  const float* xr = x + (size_t)t * HD;
  float s = 0.f;
  for (int i = threadIdx.x; i < HD; i += 256) { float v = xr[i]; s += v * v; }
#pragma unroll
  for (int o = 32; o > 0; o >>= 1) s += __shfl_down(s, o);
  __shared__ float red[4];
  if ((threadIdx.x & 63) == 0) red[threadIdx.x >> 6] = s;
  __syncthreads();
  float tot = red[0] + red[1] + red[2] + red[3];
  float rinv = rsqrtf(tot / (float)HD + 1e-5f);
  for (int i = threadIdx.x; i < HD; i += 256) {
    float v = xr[i] * rinv * nsc[i];
    tf[(size_t)t * HD + i] = v;
    tb[(size_t)t * HD + i] = __float2bfloat16(v);
  }
}

// ---------------- Router ----------------
__global__ __launch_bounds__(256)
void router_k(const float* __restrict__ tf, const float* __restrict__ gw,
              const float* __restrict__ gb, float* __restrict__ wpair,
              int* __restrict__ cnt, int* __restrict__ tok_list, int* __restrict__ pair_list)
{
  int t = blockIdx.x;
  int tid = threadIdx.x;
  int e = tid >> 4, l16 = tid & 15;
  const float* tr = tf + (size_t)t * HD;
  float s = 0.f;
  for (int i = l16; i < HD; i += 16) s += tr[i] * gw[e * HD + i];
#pragma unroll
  for (int o = 1; o < 16; o <<= 1) s += __shfl_xor(s, o);
  __shared__ float logits[NEXP];
  if (l16 == 0) logits[e] = s + gb[e];
  __syncthreads();
  if (tid == 0) {
    float v[NEXP];
#pragma unroll
    for (int i = 0; i < NEXP; ++i) v[i] = logits[i];
    int idx[TOPK]; float val[TOPK];
#pragma unroll
    for (int k = 0; k < TOPK; ++k) {
      int bi = 0; float bv = -1e30f;
      for (int i = 0; i < NEXP; ++i) if (v[i] > bv) { bv = v[i]; bi = i; }
      idx[k] = bi; val[k] = bv; v[bi] = -1e30f;
    }
    float mx = val[0], sum = 0.f, w[TOPK];
#pragma unroll
    for (int k = 0; k < TOPK; ++k) { w[k] = __expf(val[k] - mx); sum += w[k]; }
#pragma unroll
    for (int k = 0; k < TOPK; ++k) {
      float wk = w[k] / sum;
      int ee = idx[k];
      int slot = atomicAdd(&cnt[ee], 1);
      tok_list[ee * NTOK + slot]  = t;
      pair_list[ee * NTOK + slot] = t * TOPK + k;
      wpair[t * TOPK + k] = wk;
    }
  }
}

#define SYNC_LGKM do { asm volatile("s_waitcnt lgkmcnt(0)" ::: "memory"); \
    __builtin_amdgcn_sched_barrier(0); __builtin_amdgcn_s_barrier(); \
    __builtin_amdgcn_sched_barrier(0); } while (0)
#define SYNC_PLAIN do { __builtin_amdgcn_sched_barrier(0); __builtin_amdgcn_s_barrier(); \
    __builtin_amdgcn_sched_barrier(0); } while (0)

// ---------------- Grouped GEMM: 128M x 64N tile, 4 waves (each 128M x 16N-frag).
// A: reg-staged into 32KB LDS dbuf (line-coalesced loads, XOR-swizzled writes).
// B: direct global->regs (PACKED: u8 nibbles from repacked L3-resident buffer;
//    else widened int32), perm-LUT dequant to bf16 carrier. R10 sync template.
template<int STAGE, bool PACKED>
__global__ __launch_bounds__(256, 4)
void moe_gemm(const __hip_bfloat16* __restrict__ Asrc,
              const void* __restrict__ Bblk_, const void* __restrict__ Bscl_,
              const float* __restrict__ Bbias,
              const int* __restrict__ cnt,
              const int* __restrict__ tok_list, const int* __restrict__ pair_list,
              __hip_bfloat16* __restrict__ h_out, float* __restrict__ o_out)
{
  constexpr int NDIM = (STAGE == 1) ? N1 : HD;
  constexpr int NF   = 1;
  const int e  = blockIdx.z;
  const int ne = cnt[e];
  const int m0 = blockIdx.y * 128;
  if (m0 >= ne) return;
  const int n0 = blockIdx.x * 64;
  const int tid = threadIdx.x;
  const int wave = tid >> 6, lane = tid & 63;
  const int l15 = lane & 15, l4 = lane >> 4;

  __shared__ __align__(16) char Abuf[2][16384];  // [128 rows][128 B] bf16, XOR-swizzled

  const int* glist = (STAGE == 1 ? tok_list : pair_list) + e * NTOK;
  const int* plist = pair_list + e * NTOK;

  // --- A reg-staging: 4 chunks/thread, line-coalesced (8 tids share a row) ---
  const char* agp[4];
  int awoff[4];
#pragma unroll
  for (int c = 0; c < 4; ++c) {
    int g    = c * 256 + tid;
    int row  = g >> 3;
    int cb   = (g & 7) * 16;
    int slot = m0 + row; if (slot > ne - 1) slot = ne - 1;
    agp[c]   = (const char*)Asrc + (size_t)glist[slot] * ROWB + cb;
    awoff[c] = row * 128 + (cb ^ ((row & 7) << 4));
  }

  // --- B per-lane fragment offsets ---
  const int wn = wave * 16;
  const int brow = n0 + wn + l15;
  unsigned bofs, srow;
  if (PACKED) {
    bofs = (unsigned)(e * NDIM + brow) * (NGRP * 16u) + (unsigned)(l4 * 4);  // bytes
    srow = (unsigned)(e * NDIM + brow) * (unsigned)NGRP;                     // bytes
  } else {
    unsigned rb = (unsigned)(e * NDIM + brow) * NGRP;
    bofs = rb * 16 + (unsigned)(l4 * 4);   // int units
    srow = rb;                             // int units
  }
  const unsigned char* Bp = (const unsigned char*)Bblk_;
  const unsigned char* Sp = (const unsigned char*)Bscl_;
  const int* Bw = (const int*)Bblk_;
  const int* Sw = (const int*)Bscl_;

  // --- A fragment LDS read offsets: 8 m-frags x 2 kk ---
  int aoff[8][2];
#pragma unroll
  for (int mf = 0; mf < 8; ++mf) {
    int row = mf * 16 + l15;
#pragma unroll
    for (int kk = 0; kk < 2; ++kk)
      aoff[mf][kk] = row * 128 + ((kk * 64 + l4 * 16) ^ ((row & 7) << 4));
  }

  f32x4 zero = {0.f, 0.f, 0.f, 0.f};
  f32x4 acc[8][NF];
#pragma unroll
  for (int a = 0; a < 8; ++a) acc[a][0] = zero;

  i32x4 Ar[4];             // staged A chunks
  unsigned q0, q1;         // raw packed B bytes (tile being loaded)
  int scx, scy;            // scales
  short8 b0, b1;           // dequanted B carrier (tile t)

  // load B(tt) raw into q/sc
  auto loadB = [&](int tt) {
    if (PACKED) {
      q0 = *(const unsigned*)(Bp + bofs + (unsigned)(tt * 32));
      q1 = *(const unsigned*)(Bp + bofs + (unsigned)(tt * 32 + 16));
      unsigned sv = *(const unsigned short*)(Sp + srow + (unsigned)(tt * 2));
      scx = (int)(sv & 255u); scy = (int)(sv >> 8);
    } else {
      i32x4 v0 = *(const i32x4*)(Bw + bofs + (unsigned)((tt * 2 + 0) * 16));
      i32x4 v1 = *(const i32x4*)(Bw + bofs + (unsigned)((tt * 2 + 1) * 16));
      q0 = (unsigned)(v0.x & 255) | ((unsigned)(v0.y & 255) << 8) |
           ((unsigned)(v0.z & 255) << 16) | ((unsigned)v0.w << 24);
      q1 = (unsigned)(v1.x & 255) | ((unsigned)(v1.y & 255) << 8) |
           ((unsigned)(v1.z & 255) << 16) | ((unsigned)v1.w << 24);
      i32x2 sv = *(const i32x2*)(Sw + srow + (unsigned)(tt * 2));
      scx = sv.x; scy = sv.y;
    }
  };

  // --- prologue ---
#pragma unroll
  for (int c = 0; c < 4; ++c) Ar[c] = *(const i32x4*)agp[c];          // A(0)
  loadB(0);                                                            // B(0)
#pragma unroll
  for (int c = 0; c < 4; ++c) *(i32x4*)(Abuf[0] + awoff[c]) = Ar[c];   // waits A(0)
  b0 = dq_frag(q0, scx);                                               // waits B(0)
  b1 = dq_frag(q1, scy);
#pragma unroll
  for (int c = 0; c < 4; ++c) Ar[c] = *(const i32x4*)(agp[c] + 128);   // A(1)
  loadB(1);                                                            // B(1)
  SYNC_LGKM;

  for (int t = 0; t < NKT; ++t) {
    const int cur = t & 1, nxt = cur ^ 1;
    int tld = t + 2; if (tld >= NKT) tld = NKT - 1;   // uniform clamp (dup loads ok)

    // W: stage A(t+1) into LDS[nxt]; compiler inserts counted vmcnt wait here
#pragma unroll
    for (int c = 0; c < 4; ++c) *(i32x4*)(Abuf[nxt] + awoff[c]) = Ar[c];
    // I_A: refill Ar with A(tld)
#pragma unroll
    for (int c = 0; c < 4; ++c) Ar[c] = *(const i32x4*)(agp[c] + tld * 128);
    SYNC_LGKM;

    // C: MFMA tile t from LDS[cur] and b(t)
    __builtin_amdgcn_s_setprio(1);
#pragma unroll
    for (int kk = 0; kk < 2; ++kk) {
      short8 bk = kk ? b1 : b0;
#pragma unroll
      for (int mf = 0; mf < 8; ++mf) {
        short8 af = *(const short8*)(Abuf[cur] + aoff[mf][kk]);
        acc[mf][0] = __builtin_amdgcn_mfma_f32_16x16x32_bf16(af, bk, acc[mf][0], 0, 0, 0);
      }
    }
    __builtin_amdgcn_s_setprio(0);

    // D: dequant q (tile t+1) -> b; compiler-counted vmcnt wait, ~1-iter cover
    b0 = dq_frag(q0, scx);
    b1 = dq_frag(q1, scy);
    // I_B: refill q with B(tld)
    loadB(tld);
    SYNC_PLAIN;
  }

  // --- epilogue ---
  if (STAGE == 1) {
#pragma unroll
    for (int ma = 0; ma < 8; ++ma) {
      int ncol = n0 + wn + l15;
      float bias = Bbias[e * NDIM + ncol];
#pragma unroll
      for (int j = 0; j < 4; ++j) {
        float u  = acc[ma][0][j] + bias;
        float up = __shfl_xor(u, 1);
        int slot = m0 + ma * 16 + l4 * 4 + j;
        if (!(lane & 1) && slot < ne) {
          float g  = fminf(u, 7.f);
          float lv = fminf(fmaxf(up, -7.f), 7.f);
          float hv = g / (1.f + __expf(-1.702f * g)) * (lv + 1.f);
          h_out[(size_t)plist[slot] * ID + (ncol >> 1)] = __float2bfloat16(hv);
        }
      }
    }
  } else {
#pragma unroll
    for (int ma = 0; ma < 8; ++ma) {
      int ncol = n0 + wn + l15;
      float bias = Bbias[e * NDIM + ncol];
#pragma unroll
      for (int j = 0; j < 4; ++j) {
        int slot = m0 + ma * 16 + l4 * 4 + j;
        if (slot < ne)
          o_out[(size_t)plist[slot] * HD + ncol] = acc[ma][0][j] + bias;
      }
    }
  }
}

// ---------------- Final combine ----------------
__global__ __launch_bounds__(256)
void final_k(const float* __restrict__ x, const float* __restrict__ obuf,
             const float* __restrict__ wpair, float* __restrict__ out)
{
  int t = blockIdx.x;
  float w0 = wpair[t * 4 + 0], w1 = wpair[t * 4 + 1];
  float w2 = wpair[t * 4 + 2], w3 = wpair[t * 4 + 3];
  const float* o0 = obuf + (size_t)(t * 4) * HD;
  for (int i = threadIdx.x; i < HD; i += 256) {
    float r = x[(size_t)t * HD + i]
            + w0 * o0[i] + w1 * o0[HD + i] + w2 * o0[2 * HD + i] + w3 * o0[3 * HD + i];
    out[(size_t)t * HD + i] = r;
  }
}

extern "C" void kernel_launch(void* const* d_in, const int* in_sizes, int n_in,
                              void* d_out, int out_size, void* d_ws, size_t ws_size,
                              hipStream_t stream)
{
  const float* x    = (const float*)d_in[0];
  const float* nsc  = (const float*)d_in[1];
  const float* gw   = (const float*)d_in[2];
  const float* gb   = (const float*)d_in[3];
  const int*   b1   = (const int*)d_in[4];
  const int*   s1   = (const int*)d_in[5];
  const float* bia1 = (const float*)d_in[6];
  const int*   b2   = (const int*)d_in[7];
  const int*   s2   = (const int*)d_in[8];
  const float* bia2 = (const float*)d_in[9];
  float* out = (float*)d_out;

  char* ws = (char*)d_ws;
  size_t off = 0;
  auto alloc = [&](size_t bytes) {
    char* p = ws + off;
    off = (off + bytes + 255) & ~(size_t)255;
    return p;
  };
  float*           tf    = (float*)alloc((size_t)NTOK * HD * 4);
  __hip_bfloat16*  tb    = (__hip_bfloat16*)alloc((size_t)NTOK * HD * 2);
  __hip_bfloat16*  hbuf  = (__hip_bfloat16*)alloc((size_t)NTOK * TOPK * ID * 2);
  float*           obuf  = (float*)alloc((size_t)NTOK * TOPK * HD * 4);
  float*           wpair = (float*)alloc(NTOK * TOPK * 4);
  int*             cnt   = (int*)alloc(64);
  int*             tokl  = (int*)alloc(NEXP * NTOK * 4);
  int*             pairl = (int*)alloc(NEXP * NTOK * 4);
  unsigned char*   pb1   = (unsigned char*)alloc(NB1);
  unsigned char*   ps1   = (unsigned char*)alloc(NS1);
  unsigned char*   pb2   = (unsigned char*)alloc(NB2);
  unsigned char*   ps2   = (unsigned char*)alloc(NS2);
  const bool packed = (off <= ws_size);

  rmsnorm_k<<<NTOK, 256, 0, stream>>>(x, nsc, tf, tb, cnt);
  router_k<<<NTOK, 256, 0, stream>>>(tf, gw, gb, wpair, cnt, tokl, pairl);
  if (packed) {
    pack_k<<<(NB1 / 16 + 255) / 256, 256, 0, stream>>>(b1, pb1, NB1 / 16);
    pack_k<<<(NS1 / 16 + 255) / 256, 256, 0, stream>>>(s1, ps1, NS1 / 16);
    pack_k<<<(NB2 / 16 + 255) / 256, 256, 0, stream>>>(b2, pb2, NB2 / 16);
    pack_k<<<(NS2 / 16 + 255) / 256, 256, 0, stream>>>(s2, ps2, NS2 / 16);
    moe_gemm<1, true><<<dim3(N1 / 64, 4, NEXP), 256, 0, stream>>>(
        tb, pb1, ps1, bia1, cnt, tokl, pairl, hbuf, nullptr);
    moe_gemm<2, true><<<dim3(HD / 64, 4, NEXP), 256, 0, stream>>>(
        hbuf, pb2, ps2, bia2, cnt, tokl, pairl, nullptr, obuf);
  } else {
    moe_gemm<1, false><<<dim3(N1 / 64, 4, NEXP), 256, 0, stream>>>(
        tb, b1, s1, bia1, cnt, tokl, pairl, hbuf, nullptr);
    moe_gemm<2, false><<<dim3(HD / 64, 4, NEXP), 256, 0, stream>>>(
        hbuf, b2, s2, bia2, cnt, tokl, pairl, nullptr, obuf);
  }
  final_k<<<NTOK, 256, 0, stream>>>(x, obuf, wpair, out);
}

// Round 12
// 479.832 us; speedup vs baseline: 1.2494x; 1.2494x over previous
//
#include <hip/hip_runtime.h>
#include <hip/hip_bf16.h>

typedef __attribute__((ext_vector_type(8))) short short8;
typedef __attribute__((ext_vector_type(4))) float f32x4;
typedef __attribute__((ext_vector_type(4))) int i32x4;
typedef __attribute__((ext_vector_type(2))) int i32x2;
typedef __attribute__((ext_vector_type(4))) unsigned u32x4;

#define NTOK 512
#define NEXP 16
#define TOPK 4
#define HD   2880
#define ID   2880
#define N1   5760   // 2*I
#define NGRP 90     // 32-value groups per row
#define NKT  45     // HD/64 K-steps
#define ROWB 5760   // A row byte stride (HD*2 == ID*2)

__device__ __forceinline__ unsigned perm(unsigned hi, unsigned lo, unsigned sel) {
  return __builtin_amdgcn_perm(hi, lo, sel);
}

// ---------------- perm-LUT MXFP4 dequant (bit-exact bf16, scale folded) ----------------
__device__ __forceinline__ u32x4 dq_word4(unsigned p, unsigned hbl, unsigned hbh,
                                          unsigned lbl, unsigned lbh) {
  unsigned ph = p >> 4;
  unsigned il = p  & 0x07070707u, sl = p  & 0x08080808u;
  unsigned ih = ph & 0x07070707u, sh = ph & 0x08080808u;
  unsigned hbL = perm(hbh, hbl, il) | (sl << 4);
  unsigned lbL = perm(lbh, lbl, il);
  unsigned hbH = perm(hbh, hbl, ih) | (sh << 4);
  unsigned lbH = perm(lbh, lbl, ih);
  unsigned mL01 = perm(hbL, lbL, 0x05010400u);
  unsigned mL23 = perm(hbL, lbL, 0x07030602u);
  unsigned mH01 = perm(hbH, lbH, 0x05010400u);
  unsigned mH23 = perm(hbH, lbH, 0x07030602u);
  u32x4 w;
  w.x = perm(mH01, mL01, 0x05040100u);
  w.y = perm(mH01, mL01, 0x07060302u);
  w.z = perm(mH23, mL23, 0x05040100u);
  w.w = perm(mH23, mL23, 0x07060302u);
  return w;
}

// one B MFMA fragment: 4 widened nibble-bytes (8 values) + scale -> short8 bf16
__device__ __forceinline__ short8 dq_frag(unsigned pk, int sc) {
  unsigned m7 = (unsigned)((127 - sc) << 7);          // sc in [118,127]
  unsigned mm = m7 | (m7 << 16);
  unsigned e10 = (0x3F00u - m7) << 16;                // entry0 stays exact 0
  unsigned e32 = 0x3FC03F80u - mm;
  unsigned e54 = 0x40404000u - mm;
  unsigned e76 = 0x40C04080u - mm;
  unsigned hbl = perm(e32, e10, 0x07050301u);
  unsigned hbh = perm(e76, e54, 0x07050301u);
  unsigned lbl = perm(e32, e10, 0x06040200u);
  unsigned lbh = perm(e76, e54, 0x06040200u);
  u32x4 w = dq_word4(pk, hbl, hbh, lbl, lbh);
  return __builtin_bit_cast(short8, w);
}

// ---------------- RMSNorm (also zeroes cnt) ----------------
__global__ __launch_bounds__(256)
void rmsnorm_k(const float* __restrict__ x, const float* __restrict__ nsc,
               float* __restrict__ tf, __hip_bfloat16* __restrict__ tb,
               int* __restrict__ cnt)
{
  int t = blockIdx.x;
  if (t == 0 && threadIdx.x < NEXP) cnt[threadIdx.x] = 0;
  const float* xr = x + (size_t)t * HD;
  float s = 0.f;
  for (int i = threadIdx.x; i < HD; i += 256) { float v = xr[i]; s += v * v; }
#pragma unroll
  for (int o = 32; o > 0; o >>= 1) s += __shfl_down(s, o);
  __shared__ float red[4];
  if ((threadIdx.x & 63) == 0) red[threadIdx.x >> 6] = s;
  __syncthreads();
  float tot = red[0] + red[1] + red[2] + red[3];
  float rinv = rsqrtf(tot / (float)HD + 1e-5f);
  for (int i = threadIdx.x; i < HD; i += 256) {
    float v = xr[i] * rinv * nsc[i];
    tf[(size_t)t * HD + i] = v;
    tb[(size_t)t * HD + i] = __float2bfloat16(v);
  }
}

// ---------------- Router ----------------
__global__ __launch_bounds__(256)
void router_k(const float* __restrict__ tf, const float* __restrict__ gw,
              const float* __restrict__ gb, float* __restrict__ wpair,
              int* __restrict__ cnt, int* __restrict__ tok_list, int* __restrict__ pair_list)
{
  int t = blockIdx.x;
  int tid = threadIdx.x;
  int e = tid >> 4, l16 = tid & 15;
  const float* tr = tf + (size_t)t * HD;
  float s = 0.f;
  for (int i = l16; i < HD; i += 16) s += tr[i] * gw[e * HD + i];
#pragma unroll
  for (int o = 1; o < 16; o <<= 1) s += __shfl_xor(s, o);
  __shared__ float logits[NEXP];
  if (l16 == 0) logits[e] = s + gb[e];
  __syncthreads();
  if (tid == 0) {
    float v[NEXP];
#pragma unroll
    for (int i = 0; i < NEXP; ++i) v[i] = logits[i];
    int idx[TOPK]; float val[TOPK];
#pragma unroll
    for (int k = 0; k < TOPK; ++k) {
      int bi = 0; float bv = -1e30f;
      for (int i = 0; i < NEXP; ++i) if (v[i] > bv) { bv = v[i]; bi = i; }
      idx[k] = bi; val[k] = bv; v[bi] = -1e30f;
    }
    float mx = val[0], sum = 0.f, w[TOPK];
#pragma unroll
    for (int k = 0; k < TOPK; ++k) { w[k] = __expf(val[k] - mx); sum += w[k]; }
#pragma unroll
    for (int k = 0; k < TOPK; ++k) {
      float wk = w[k] / sum;
      int ee = idx[k];
      int slot = atomicAdd(&cnt[ee], 1);
      tok_list[ee * NTOK + slot]  = t;
      pair_list[ee * NTOK + slot] = t * TOPK + k;
      wpair[t * TOPK + k] = wk;
    }
  }
}

#define SYNC_LGKM do { asm volatile("s_waitcnt lgkmcnt(0)" ::: "memory"); \
    __builtin_amdgcn_sched_barrier(0); __builtin_amdgcn_s_barrier(); \
    __builtin_amdgcn_sched_barrier(0); } while (0)

// ---------------- Grouped GEMM: 128M x 64N tile, 4 waves, ONE barrier per K-step.
// A: reg-staged into 32KB LDS dbuf (line-coalesced loads, XOR-swizzled writes).
// B: direct global->regs (widened int32), perm-LUT dequant to bf16 carrier.
// Iteration: W(A t+1 -> buf[nxt]) ; I_A(A t+2) ; MFMA(buf[cur], B t) ;
//            D(dequant B t+1) ; I_B(B t+2) ; SYNC_LGKM.
// dbuf => no intra-iteration hazard; single end barrier drains ds_writes.
template<int STAGE>
__global__ __launch_bounds__(256, 4)
void moe_gemm(const __hip_bfloat16* __restrict__ Asrc,
              const int* __restrict__ Bblk, const int* __restrict__ Bscl,
              const float* __restrict__ Bbias,
              const int* __restrict__ cnt,
              const int* __restrict__ tok_list, const int* __restrict__ pair_list,
              __hip_bfloat16* __restrict__ h_out, float* __restrict__ o_out)
{
  constexpr int NDIM = (STAGE == 1) ? N1 : HD;
  const int e  = blockIdx.z;
  const int ne = cnt[e];
  const int m0 = blockIdx.y * 128;
  if (m0 >= ne) return;
  const int n0 = blockIdx.x * 64;
  const int tid = threadIdx.x;
  const int wave = tid >> 6, lane = tid & 63;
  const int l15 = lane & 15, l4 = lane >> 4;

  __shared__ __align__(16) char Abuf[2][16384];  // [128 rows][128 B] bf16, XOR-swizzled

  const int* glist = (STAGE == 1 ? tok_list : pair_list) + e * NTOK;
  const int* plist = pair_list + e * NTOK;

  // --- A reg-staging: 4 chunks/thread, line-coalesced (8 tids share a row) ---
  const char* agp[4];
  int awoff[4];
#pragma unroll
  for (int c = 0; c < 4; ++c) {
    int g    = c * 256 + tid;
    int row  = g >> 3;
    int cb   = (g & 7) * 16;
    int slot = m0 + row; if (slot > ne - 1) slot = ne - 1;
    agp[c]   = (const char*)Asrc + (size_t)glist[slot] * ROWB + cb;
    awoff[c] = row * 128 + (cb ^ ((row & 7) << 4));
  }

  // --- B per-lane fragment offsets (int units) ---
  const int wn = wave * 16;
  const int brow = n0 + wn + l15;
  const unsigned rb = (unsigned)(e * NDIM + brow) * NGRP;
  const unsigned bofs = rb * 16 + (unsigned)(l4 * 4);
  const unsigned srow = rb;

  // --- A fragment LDS read offsets: 8 m-frags x 2 kk ---
  int aoff[8][2];
#pragma unroll
  for (int mf = 0; mf < 8; ++mf) {
    int row = mf * 16 + l15;
#pragma unroll
    for (int kk = 0; kk < 2; ++kk)
      aoff[mf][kk] = row * 128 + ((kk * 64 + l4 * 16) ^ ((row & 7) << 4));
  }

  f32x4 zero = {0.f, 0.f, 0.f, 0.f};
  f32x4 acc[8];
#pragma unroll
  for (int a = 0; a < 8; ++a) acc[a] = zero;

  i32x4 Ar[4];             // staged A chunks (tile t+1 at loop top)
  unsigned q0, q1;         // raw B nibble words (tile t+1 at loop top)
  int scx, scy;            // scales
  short8 b0, b1;           // dequanted B (tile t at loop top)

  auto loadB = [&](int tt) {
    i32x4 v0 = *(const i32x4*)(Bblk + bofs + (unsigned)((tt * 2 + 0) * 16));
    i32x4 v1 = *(const i32x4*)(Bblk + bofs + (unsigned)((tt * 2 + 1) * 16));
    q0 = (unsigned)(v0.x & 255) | ((unsigned)(v0.y & 255) << 8) |
         ((unsigned)(v0.z & 255) << 16) | ((unsigned)v0.w << 24);
    q1 = (unsigned)(v1.x & 255) | ((unsigned)(v1.y & 255) << 8) |
         ((unsigned)(v1.z & 255) << 16) | ((unsigned)v1.w << 24);
    i32x2 sv = *(const i32x2*)(Bscl + srow + (unsigned)(tt * 2));
    scx = sv.x; scy = sv.y;
  };

  // --- prologue: buf0 <- A(0); b <- B(0); Ar <- A(1); q <- B(1) ---
#pragma unroll
  for (int c = 0; c < 4; ++c) Ar[c] = *(const i32x4*)agp[c];
  loadB(0);
#pragma unroll
  for (int c = 0; c < 4; ++c) *(i32x4*)(Abuf[0] + awoff[c]) = Ar[c];
  b0 = dq_frag(q0, scx);
  b1 = dq_frag(q1, scy);
#pragma unroll
  for (int c = 0; c < 4; ++c) Ar[c] = *(const i32x4*)(agp[c] + 128);
  loadB(1);
  SYNC_LGKM;

  for (int t = 0; t < NKT; ++t) {
    const int cur = t & 1, nxt = cur ^ 1;
    int tld = t + 2; if (tld >= NKT) tld = NKT - 1;   // uniform clamp (dup loads ok)

    // W: stage A(t+1) into LDS[nxt]; compiler inserts counted vmcnt wait
#pragma unroll
    for (int c = 0; c < 4; ++c) *(i32x4*)(Abuf[nxt] + awoff[c]) = Ar[c];
    // I_A: refill Ar with A(tld)
#pragma unroll
    for (int c = 0; c < 4; ++c) Ar[c] = *(const i32x4*)(agp[c] + tld * 128);

    // C: MFMA tile t from LDS[cur] (writes drained at previous end barrier) and b(t)
    __builtin_amdgcn_s_setprio(1);
#pragma unroll
    for (int kk = 0; kk < 2; ++kk) {
      short8 bk = kk ? b1 : b0;
#pragma unroll
      for (int mf = 0; mf < 8; ++mf) {
        short8 af = *(const short8*)(Abuf[cur] + aoff[mf][kk]);
        acc[mf] = __builtin_amdgcn_mfma_f32_16x16x32_bf16(af, bk, acc[mf], 0, 0, 0);
      }
    }
    __builtin_amdgcn_s_setprio(0);

    // D: dequant q (tile t+1) -> b; ~1.3-iter cover on the B loads
    b0 = dq_frag(q0, scx);
    b1 = dq_frag(q1, scy);
    // I_B: refill q with B(tld)
    loadB(tld);

    SYNC_LGKM;   // single rendezvous: drains my ds_writes; protects dbuf swap
  }

  // --- epilogue ---
  if (STAGE == 1) {
#pragma unroll
    for (int ma = 0; ma < 8; ++ma) {
      int ncol = n0 + wn + l15;
      float bias = Bbias[e * NDIM + ncol];
#pragma unroll
      for (int j = 0; j < 4; ++j) {
        float u  = acc[ma][j] + bias;
        float up = __shfl_xor(u, 1);
        int slot = m0 + ma * 16 + l4 * 4 + j;
        if (!(lane & 1) && slot < ne) {
          float g  = fminf(u, 7.f);
          float lv = fminf(fmaxf(up, -7.f), 7.f);
          float hv = g / (1.f + __expf(-1.702f * g)) * (lv + 1.f);
          h_out[(size_t)plist[slot] * ID + (ncol >> 1)] = __float2bfloat16(hv);
        }
      }
    }
  } else {
#pragma unroll
    for (int ma = 0; ma < 8; ++ma) {
      int ncol = n0 + wn + l15;
      float bias = Bbias[e * NDIM + ncol];
#pragma unroll
      for (int j = 0; j < 4; ++j) {
        int slot = m0 + ma * 16 + l4 * 4 + j;
        if (slot < ne)
          o_out[(size_t)plist[slot] * HD + ncol] = acc[ma][j] + bias;
      }
    }
  }
}

// ---------------- Final combine ----------------
__global__ __launch_bounds__(256)
void final_k(const float* __restrict__ x, const float* __restrict__ obuf,
             const float* __restrict__ wpair, float* __restrict__ out)
{
  int t = blockIdx.x;
  float w0 = wpair[t * 4 + 0], w1 = wpair[t * 4 + 1];
  float w2 = wpair[t * 4 + 2], w3 = wpair[t * 4 + 3];
  const float* o0 = obuf + (size_t)(t * 4) * HD;
  for (int i = threadIdx.x; i < HD; i += 256) {
    float r = x[(size_t)t * HD + i]
            + w0 * o0[i] + w1 * o0[HD + i] + w2 * o0[2 * HD + i] + w3 * o0[3 * HD + i];
    out[(size_t)t * HD + i] = r;
  }
}

extern "C" void kernel_launch(void* const* d_in, const int* in_sizes, int n_in,
                              void* d_out, int out_size, void* d_ws, size_t ws_size,
                              hipStream_t stream)
{
  const float* x    = (const float*)d_in[0];
  const float* nsc  = (const float*)d_in[1];
  const float* gw   = (const float*)d_in[2];
  const float* gb   = (const float*)d_in[3];
  const int*   b1   = (const int*)d_in[4];
  const int*   s1   = (const int*)d_in[5];
  const float* bia1 = (const float*)d_in[6];
  const int*   b2   = (const int*)d_in[7];
  const int*   s2   = (const int*)d_in[8];
  const float* bia2 = (const float*)d_in[9];
  float* out = (float*)d_out;

  char* ws = (char*)d_ws;
  size_t off = 0;
  auto alloc = [&](size_t bytes) {
    char* p = ws + off;
    off = (off + bytes + 255) & ~(size_t)255;
    return p;
  };
  float*           tf    = (float*)alloc((size_t)NTOK * HD * 4);
  __hip_bfloat16*  tb    = (__hip_bfloat16*)alloc((size_t)NTOK * HD * 2);
  __hip_bfloat16*  hbuf  = (__hip_bfloat16*)alloc((size_t)NTOK * TOPK * ID * 2);
  float*           obuf  = (float*)alloc((size_t)NTOK * TOPK * HD * 4);
  float*           wpair = (float*)alloc(NTOK * TOPK * 4);
  int*             cnt   = (int*)alloc(64);
  int*             tokl  = (int*)alloc(NEXP * NTOK * 4);
  int*             pairl = (int*)alloc(NEXP * NTOK * 4);

  rmsnorm_k<<<NTOK, 256, 0, stream>>>(x, nsc, tf, tb, cnt);
  router_k<<<NTOK, 256, 0, stream>>>(tf, gw, gb, wpair, cnt, tokl, pairl);
  moe_gemm<1><<<dim3(N1 / 64, 4, NEXP), 256, 0, stream>>>(tb, b1, s1, bia1, cnt, tokl, pairl, hbuf, nullptr);
  moe_gemm<2><<<dim3(HD / 64, 4, NEXP), 256, 0, stream>>>(hbuf, b2, s2, bia2, cnt, tokl, pairl, nullptr, obuf);
  final_k<<<NTOK, 256, 0, stream>>>(x, obuf, wpair, out);
}

// Round 13
// 467.733 us; speedup vs baseline: 1.2817x; 1.0259x over previous
//
#include <hip/hip_runtime.h>
#include <hip/hip_bf16.h>

typedef __attribute__((ext_vector_type(8))) short short8;
typedef __attribute__((ext_vector_type(4))) float f32x4;
typedef __attribute__((ext_vector_type(4))) int i32x4;
typedef __attribute__((ext_vector_type(2))) int i32x2;
typedef __attribute__((ext_vector_type(4))) unsigned u32x4;

#define NTOK 512
#define NEXP 16
#define TOPK 4
#define HD   2880
#define ID   2880
#define N1   5760   // 2*I
#define NGRP 90     // 32-value groups per row
#define NKT  45     // HD/64 K-steps (= 15 x 3)
#define ROWB 5760   // A row byte stride (HD*2 == ID*2)

__device__ __forceinline__ unsigned perm(unsigned hi, unsigned lo, unsigned sel) {
  return __builtin_amdgcn_perm(hi, lo, sel);
}

// ---------------- perm-LUT MXFP4 dequant (bit-exact bf16, scale folded) ----------------
__device__ __forceinline__ u32x4 dq_word4(unsigned p, unsigned hbl, unsigned hbh,
                                          unsigned lbl, unsigned lbh) {
  unsigned ph = p >> 4;
  unsigned il = p  & 0x07070707u, sl = p  & 0x08080808u;
  unsigned ih = ph & 0x07070707u, sh = ph & 0x08080808u;
  unsigned hbL = perm(hbh, hbl, il) | (sl << 4);
  unsigned lbL = perm(lbh, lbl, il);
  unsigned hbH = perm(hbh, hbl, ih) | (sh << 4);
  unsigned lbH = perm(lbh, lbl, ih);
  unsigned mL01 = perm(hbL, lbL, 0x05010400u);
  unsigned mL23 = perm(hbL, lbL, 0x07030602u);
  unsigned mH01 = perm(hbH, lbH, 0x05010400u);
  unsigned mH23 = perm(hbH, lbH, 0x07030602u);
  u32x4 w;
  w.x = perm(mH01, mL01, 0x05040100u);
  w.y = perm(mH01, mL01, 0x07060302u);
  w.z = perm(mH23, mL23, 0x05040100u);
  w.w = perm(mH23, mL23, 0x07060302u);
  return w;
}

// one B MFMA fragment: 4 widened nibble-bytes (8 values) + scale -> short8 bf16
__device__ __forceinline__ short8 dq_frag(unsigned pk, int sc) {
  unsigned m7 = (unsigned)((127 - sc) << 7);          // sc in [118,127]
  unsigned mm = m7 | (m7 << 16);
  unsigned e10 = (0x3F00u - m7) << 16;                // entry0 stays exact 0
  unsigned e32 = 0x3FC03F80u - mm;
  unsigned e54 = 0x40404000u - mm;
  unsigned e76 = 0x40C04080u - mm;
  unsigned hbl = perm(e32, e10, 0x07050301u);
  unsigned hbh = perm(e76, e54, 0x07050301u);
  unsigned lbl = perm(e32, e10, 0x06040200u);
  unsigned lbh = perm(e76, e54, 0x06040200u);
  u32x4 w = dq_word4(pk, hbl, hbh, lbl, lbh);
  return __builtin_bit_cast(short8, w);
}

__device__ __forceinline__ unsigned pack8(i32x4 v) {
  return (unsigned)(v.x & 255) | ((unsigned)(v.y & 255) << 8) |
         ((unsigned)(v.z & 255) << 16) | ((unsigned)v.w << 24);
}

// ---------------- RMSNorm (also zeroes cnt) ----------------
__global__ __launch_bounds__(256)
void rmsnorm_k(const float* __restrict__ x, const float* __restrict__ nsc,
               float* __restrict__ tf, __hip_bfloat16* __restrict__ tb,
               int* __restrict__ cnt)
{
  int t = blockIdx.x;
  if (t == 0 && threadIdx.x < NEXP) cnt[threadIdx.x] = 0;
  const float* xr = x + (size_t)t * HD;
  float s = 0.f;
  for (int i = threadIdx.x; i < HD; i += 256) { float v = xr[i]; s += v * v; }
#pragma unroll
  for (int o = 32; o > 0; o >>= 1) s += __shfl_down(s, o);
  __shared__ float red[4];
  if ((threadIdx.x & 63) == 0) red[threadIdx.x >> 6] = s;
  __syncthreads();
  float tot = red[0] + red[1] + red[2] + red[3];
  float rinv = rsqrtf(tot / (float)HD + 1e-5f);
  for (int i = threadIdx.x; i < HD; i += 256) {
    float v = xr[i] * rinv * nsc[i];
    tf[(size_t)t * HD + i] = v;
    tb[(size_t)t * HD + i] = __float2bfloat16(v);
  }
}

// ---------------- Router ----------------
__global__ __launch_bounds__(256)
void router_k(const float* __restrict__ tf, const float* __restrict__ gw,
              const float* __restrict__ gb, float* __restrict__ wpair,
              int* __restrict__ cnt, int* __restrict__ tok_list, int* __restrict__ pair_list)
{
  int t = blockIdx.x;
  int tid = threadIdx.x;
  int e = tid >> 4, l16 = tid & 15;
  const float* tr = tf + (size_t)t * HD;
  float s = 0.f;
  for (int i = l16; i < HD; i += 16) s += tr[i] * gw[e * HD + i];
#pragma unroll
  for (int o = 1; o < 16; o <<= 1) s += __shfl_xor(s, o);
  __shared__ float logits[NEXP];
  if (l16 == 0) logits[e] = s + gb[e];
  __syncthreads();
  if (tid == 0) {
    float v[NEXP];
#pragma unroll
    for (int i = 0; i < NEXP; ++i) v[i] = logits[i];
    int idx[TOPK]; float val[TOPK];
#pragma unroll
    for (int k = 0; k < TOPK; ++k) {
      int bi = 0; float bv = -1e30f;
      for (int i = 0; i < NEXP; ++i) if (v[i] > bv) { bv = v[i]; bi = i; }
      idx[k] = bi; val[k] = bv; v[bi] = -1e30f;
    }
    float mx = val[0], sum = 0.f, w[TOPK];
#pragma unroll
    for (int k = 0; k < TOPK; ++k) { w[k] = __expf(val[k] - mx); sum += w[k]; }
#pragma unroll
    for (int k = 0; k < TOPK; ++k) {
      float wk = w[k] / sum;
      int ee = idx[k];
      int slot = atomicAdd(&cnt[ee], 1);
      tok_list[ee * NTOK + slot]  = t;
      pair_list[ee * NTOK + slot] = t * TOPK + k;
      wpair[t * TOPK + k] = wk;
    }
  }
}

#define SYNC_LGKM do { asm volatile("s_waitcnt lgkmcnt(0)" ::: "memory"); \
    __builtin_amdgcn_sched_barrier(0); __builtin_amdgcn_s_barrier(); \
    __builtin_amdgcn_sched_barrier(0); } while (0)

// ---------------- Grouped GEMM: 128M x 64N tile, 4 waves, one barrier per K-step.
// B prefetch depth-3: three named raw register sets; the vmcnt wait for a set
// happens at its pack+dequant TWO+ iterations after issue (compiler-counted).
// A: reg-staged into 32KB LDS dbuf (line-coalesced loads, XOR-swizzled writes).
template<int STAGE>
__global__ __launch_bounds__(256, 3)
void moe_gemm(const __hip_bfloat16* __restrict__ Asrc,
              const int* __restrict__ Bblk, const int* __restrict__ Bscl,
              const float* __restrict__ Bbias,
              const int* __restrict__ cnt,
              const int* __restrict__ tok_list, const int* __restrict__ pair_list,
              __hip_bfloat16* __restrict__ h_out, float* __restrict__ o_out)
{
  constexpr int NDIM = (STAGE == 1) ? N1 : HD;
  const int e  = blockIdx.z;
  const int ne = cnt[e];
  const int m0 = blockIdx.y * 128;
  if (m0 >= ne) return;
  const int n0 = blockIdx.x * 64;
  const int tid = threadIdx.x;
  const int wave = tid >> 6, lane = tid & 63;
  const int l15 = lane & 15, l4 = lane >> 4;

  __shared__ __align__(16) char Abuf[2][16384];  // [128 rows][128 B] bf16, XOR-swizzled

  const int* glist = (STAGE == 1 ? tok_list : pair_list) + e * NTOK;
  const int* plist = pair_list + e * NTOK;

  // --- A reg-staging: 4 chunks/thread, line-coalesced (8 tids share a row) ---
  const char* agp[4];
  int awoff[4];
#pragma unroll
  for (int c = 0; c < 4; ++c) {
    int g    = c * 256 + tid;
    int row  = g >> 3;
    int cb   = (g & 7) * 16;
    int slot = m0 + row; if (slot > ne - 1) slot = ne - 1;
    agp[c]   = (const char*)Asrc + (size_t)glist[slot] * ROWB + cb;
    awoff[c] = row * 128 + (cb ^ ((row & 7) << 4));
  }

  // --- B per-lane fragment offsets (int units) ---
  const int wn = wave * 16;
  const int brow = n0 + wn + l15;
  const unsigned rb = (unsigned)(e * NDIM + brow) * NGRP;
  const unsigned bofs = rb * 16 + (unsigned)(l4 * 4);
  const unsigned srow = rb;

  // --- A fragment LDS read offsets: 8 m-frags x 2 kk ---
  int aoff[8][2];
#pragma unroll
  for (int mf = 0; mf < 8; ++mf) {
    int row = mf * 16 + l15;
#pragma unroll
    for (int kk = 0; kk < 2; ++kk)
      aoff[mf][kk] = row * 128 + ((kk * 64 + l4 * 16) ^ ((row & 7) << 4));
  }

  f32x4 zero = {0.f, 0.f, 0.f, 0.f};
  f32x4 acc[8];
#pragma unroll
  for (int a = 0; a < 8; ++a) acc[a] = zero;

  i32x4 Ar[4];                    // staged A chunks (tile t+1 at loop top)
  // three named raw B sets (depth-3); raw until D-phase pack+dequant
  i32x4 q0a, q0b; i32x2 s0;       // set 0
  i32x4 q1a, q1b; i32x2 s1;       // set 1
  i32x4 q2a, q2b; i32x2 s2;       // set 2
  short8 b0, b1;                  // dequanted B (tile t at MFMA)

#define LOADB(QA, QB, SS, tt) do { \
    QA = *(const i32x4*)(Bblk + bofs + (unsigned)(((tt) * 2 + 0) * 16)); \
    QB = *(const i32x4*)(Bblk + bofs + (unsigned)(((tt) * 2 + 1) * 16)); \
    SS = *(const i32x2*)(Bscl + srow + (unsigned)((tt) * 2)); } while (0)

  // --- prologue: A(0)->LDS0, Ar<-A(1); raw sets <- B(0),B(1),B(2); b <- dq(B0) ---
#pragma unroll
  for (int c = 0; c < 4; ++c) Ar[c] = *(const i32x4*)agp[c];
  LOADB(q0a, q0b, s0, 0);
  LOADB(q1a, q1b, s1, 1);
  LOADB(q2a, q2b, s2, 2);
#pragma unroll
  for (int c = 0; c < 4; ++c) *(i32x4*)(Abuf[0] + awoff[c]) = Ar[c];  // waits A(0) only
  b0 = dq_frag(pack8(q0a), s0.x);                                     // waits B(0) only
  b1 = dq_frag(pack8(q0b), s0.y);
#pragma unroll
  for (int c = 0; c < 4; ++c) Ar[c] = *(const i32x4*)(agp[c] + 128);  // A(1)
  SYNC_LGKM;

  // body for tile t: D-phase uses set SD=(t+1)%3, refills set SF=t%3 with B(t+3)
#define BODY(t, QDa, QDb, SD, QFa, QFb, SF) do { \
    const int cur = (t) & 1, nxt = cur ^ 1; \
    int tldA = (t) + 2; if (tldA >= NKT) tldA = NKT - 1; \
    int tldB = (t) + 3; if (tldB >= NKT) tldB = NKT - 1; \
    _Pragma("unroll") \
    for (int c = 0; c < 4; ++c) *(i32x4*)(Abuf[nxt] + awoff[c]) = Ar[c]; \
    _Pragma("unroll") \
    for (int c = 0; c < 4; ++c) Ar[c] = *(const i32x4*)(agp[c] + tldA * 128); \
    __builtin_amdgcn_s_setprio(1); \
    _Pragma("unroll") \
    for (int kk = 0; kk < 2; ++kk) { \
      short8 bk = kk ? b1 : b0; \
      _Pragma("unroll") \
      for (int mf = 0; mf < 8; ++mf) { \
        short8 af = *(const short8*)(Abuf[cur] + aoff[mf][kk]); \
        acc[mf] = __builtin_amdgcn_mfma_f32_16x16x32_bf16(af, bk, acc[mf], 0, 0, 0); \
      } \
    } \
    __builtin_amdgcn_s_setprio(0); \
    b0 = dq_frag(pack8(QDa), SD.x); \
    b1 = dq_frag(pack8(QDb), SD.y); \
    LOADB(QFa, QFb, SF, tldB); \
    SYNC_LGKM; \
  } while (0)

  for (int tp = 0; tp < NKT / 3; ++tp) {
    const int t = 3 * tp;
    BODY(t + 0, q1a, q1b, s1, q0a, q0b, s0);  // dq set1 (tile t+1), refill set0 <- B(t+3)
    BODY(t + 1, q2a, q2b, s2, q1a, q1b, s1);  // dq set2 (tile t+2), refill set1 <- B(t+4)
    BODY(t + 2, q0a, q0b, s0, q2a, q2b, s2);  // dq set0 (tile t+3), refill set2 <- B(t+5)
  }
#undef BODY
#undef LOADB

  // --- epilogue ---
  if (STAGE == 1) {
#pragma unroll
    for (int ma = 0; ma < 8; ++ma) {
      int ncol = n0 + wn + l15;
      float bias = Bbias[e * NDIM + ncol];
#pragma unroll
      for (int j = 0; j < 4; ++j) {
        float u  = acc[ma][j] + bias;
        float up = __shfl_xor(u, 1);
        int slot = m0 + ma * 16 + l4 * 4 + j;
        if (!(lane & 1) && slot < ne) {
          float g  = fminf(u, 7.f);
          float lv = fminf(fmaxf(up, -7.f), 7.f);
          float hv = g / (1.f + __expf(-1.702f * g)) * (lv + 1.f);
          h_out[(size_t)plist[slot] * ID + (ncol >> 1)] = __float2bfloat16(hv);
        }
      }
    }
  } else {
#pragma unroll
    for (int ma = 0; ma < 8; ++ma) {
      int ncol = n0 + wn + l15;
      float bias = Bbias[e * NDIM + ncol];
#pragma unroll
      for (int j = 0; j < 4; ++j) {
        int slot = m0 + ma * 16 + l4 * 4 + j;
        if (slot < ne)
          o_out[(size_t)plist[slot] * HD + ncol] = acc[ma][j] + bias;
      }
    }
  }
}

// ---------------- Final combine ----------------
__global__ __launch_bounds__(256)
void final_k(const float* __restrict__ x, const float* __restrict__ obuf,
             const float* __restrict__ wpair, float* __restrict__ out)
{
  int t = blockIdx.x;
  float w0 = wpair[t * 4 + 0], w1 = wpair[t * 4 + 1];
  float w2 = wpair[t * 4 + 2], w3 = wpair[t * 4 + 3];
  const float* o0 = obuf + (size_t)(t * 4) * HD;
  for (int i = threadIdx.x; i < HD; i += 256) {
    float r = x[(size_t)t * HD + i]
            + w0 * o0[i] + w1 * o0[HD + i] + w2 * o0[2 * HD + i] + w3 * o0[3 * HD + i];
    out[(size_t)t * HD + i] = r;
  }
}

extern "C" void kernel_launch(void* const* d_in, const int* in_sizes, int n_in,
                              void* d_out, int out_size, void* d_ws, size_t ws_size,
                              hipStream_t stream)
{
  const float* x    = (const float*)d_in[0];
  const float* nsc  = (const float*)d_in[1];
  const float* gw   = (const float*)d_in[2];
  const float* gb   = (const float*)d_in[3];
  const int*   b1   = (const int*)d_in[4];
  const int*   s1   = (const int*)d_in[5];
  const float* bia1 = (const float*)d_in[6];
  const int*   b2   = (const int*)d_in[7];
  const int*   s2   = (const int*)d_in[8];
  const float* bia2 = (const float*)d_in[9];
  float* out = (float*)d_out;

  char* ws = (char*)d_ws;
  size_t off = 0;
  auto alloc = [&](size_t bytes) {
    char* p = ws + off;
    off = (off + bytes + 255) & ~(size_t)255;
    return p;
  };
  float*           tf    = (float*)alloc((size_t)NTOK * HD * 4);
  __hip_bfloat16*  tb    = (__hip_bfloat16*)alloc((size_t)NTOK * HD * 2);
  __hip_bfloat16*  hbuf  = (__hip_bfloat16*)alloc((size_t)NTOK * TOPK * ID * 2);
  float*           obuf  = (float*)alloc((size_t)NTOK * TOPK * HD * 4);
  float*           wpair = (float*)alloc(NTOK * TOPK * 4);
  int*             cnt   = (int*)alloc(64);
  int*             tokl  = (int*)alloc(NEXP * NTOK * 4);
  int*             pairl = (int*)alloc(NEXP * NTOK * 4);

  rmsnorm_k<<<NTOK, 256, 0, stream>>>(x, nsc, tf, tb, cnt);
  router_k<<<NTOK, 256, 0, stream>>>(tf, gw, gb, wpair, cnt, tokl, pairl);
  moe_gemm<1><<<dim3(N1 / 64, 4, NEXP), 256, 0, stream>>>(tb, b1, s1, bia1, cnt, tokl, pairl, hbuf, nullptr);
  moe_gemm<2><<<dim3(HD / 64, 4, NEXP), 256, 0, stream>>>(hbuf, b2, s2, bia2, cnt, tokl, pairl, nullptr, obuf);
  final_k<<<NTOK, 256, 0, stream>>>(x, obuf, wpair, out);
}